// Round 12
// baseline (265.885 us; speedup 1.0000x reference)
//
#include <hip/hip_runtime.h>
#include <hip/hip_bf16.h>
#include <cstdint>

// out[M,N] = x[M,K] @ weight[N,K]^T, fp32 device buffers.
// TWO plain (graph-capturable) dispatches:
//   1) reset_cnt<<<1,1>>>: atomicExch(counter, 0)   [coherent-point write]
//   2) persist_cvt_gemm<<<256,512>>> (1 block/CU, co-resident):
//      phase 1: cvt fp32->bf16 into d_ws (tiled fragment-ordered layout)
//      hand-rolled agent-scope atomic grid barrier (fence+add+acquire spin)
//      phase 2: 256x256 GEMM, BK=64, 8 waves, publish-once vmcnt(2) K-step
//      (R7 structure: best rocprof-measured, 243-246 us with profiling).
// Rationale: hipLaunchCooperativeKernel is not graph-capturable -> R6-R11
// timed runs silently captured the fallback (constant 265.x us). This makes
// the validated path == the timed path.

typedef __bf16 bf16x8 __attribute__((ext_vector_type(8)));
typedef float f32x4 __attribute__((ext_vector_type(4)));
typedef unsigned short u16x8 __attribute__((ext_vector_type(8)));

#define GAS __attribute__((address_space(1)))
#define LAS __attribute__((address_space(3)))
#define ASYNC16(gsrc, ldst)                                                  \
    __builtin_amdgcn_global_load_lds((GAS uint32_t*)(const void*)(gsrc),     \
                                     (LAS uint32_t*)(ldst), 16, 0, 0)

__device__ inline unsigned short f2bf(float f) {
    __hip_bfloat16 h = __float2bfloat16(f);  // RNE
    return *reinterpret_cast<unsigned short*>(&h);
}

__global__ void reset_cnt(unsigned int* cnt) {
    atomicExch(cnt, 0u);   // device-scope RMW at coherent point
}

__global__ __launch_bounds__(512, 1) void persist_cvt_gemm(
    const float* __restrict__ A32,       // x      [M,K]
    const float* __restrict__ B32,       // weight [N,K]
    unsigned short* __restrict__ ws,     // bf16 tiled [szX | szW]
    unsigned int* __restrict__ cnt,      // grid-barrier counter (reset to 0)
    float* __restrict__ C,               // out    [M,N]
    int M, int N, int K)
{
    const int NT  = K >> 6;              // 64 K-steps
    const int szX = M * K;
    const int szW = N * K;

    // ================= phase 1: cvt fp32 -> tiled bf16 ws =================
    // chunk (16384 shorts) per (tile,kt); within: off = ks*8192 + g*2048 +
    // row*8, k = kt*64 + ks*32 + g*8.  (layout validated R7/R8)
    {
        const int nA8  = szX >> 3;
        const int tot8 = (szX + szW) >> 3;
        const int S = gridDim.x * blockDim.x;
        for (int c = blockIdx.x * blockDim.x + threadIdx.x; c < tot8; c += S) {
            unsigned short* dst = ws + ((size_t)c << 3);
            int cl; const float* base;
            if (c < nA8) { cl = c;       base = A32; }
            else         { cl = c - nA8; base = B32; }
            const int cid  = cl >> 11;
            const int c_in = cl & 2047;
            const float* src = base +
                (size_t)((cid >> 6) * 256 + (c_in & 255)) * K +
                (cid & 63) * 64 + (c_in >> 10) * 32 + ((c_in >> 8) & 3) * 8;
            float4 v0 = *reinterpret_cast<const float4*>(src);
            float4 v1 = *reinterpret_cast<const float4*>(src + 4);
            u16x8 o;
            o[0] = f2bf(v0.x); o[1] = f2bf(v0.y); o[2] = f2bf(v0.z); o[3] = f2bf(v0.w);
            o[4] = f2bf(v1.x); o[5] = f2bf(v1.y); o[6] = f2bf(v1.z); o[7] = f2bf(v1.w);
            *reinterpret_cast<u16x8*>(dst) = o;
        }
    }

    // ============ hand-rolled grid barrier (agent scope) ============
    // __syncthreads drains each wave's vmcnt before s_barrier; thread0's
    // release fence writes back this XCD's L2; acquire spin-load invalidates
    // L1+L2 before any post-barrier ws read on this XCD.
    {
        __syncthreads();
        if (threadIdx.x == 0) {
            __threadfence();  // agent-scope release (L2 writeback)
            __hip_atomic_fetch_add(cnt, 1u, __ATOMIC_ACQ_REL, __HIP_MEMORY_SCOPE_AGENT);
            while (__hip_atomic_load(cnt, __ATOMIC_ACQUIRE, __HIP_MEMORY_SCOPE_AGENT)
                   < gridDim.x) {
                __builtin_amdgcn_s_sleep(2);
            }
        }
        __syncthreads();
    }
    asm volatile("s_waitcnt vmcnt(0)" ::: "memory");   // clean vmcnt ledger

    // ================= phase 2: GEMM (R7 publish-once structure) ==========
    __shared__ unsigned short lds[2][2][16384];  // [set][A|B] = 128 KB

    const int nbm = M >> 8;              // 8
    const int nbn = N >> 8;              // 32
    const int bid = blockIdx.x;
    const int swzid = (bid & 7) * ((nbm * nbn) >> 3) + (bid >> 3);
    const int bm = swzid % nbm;          // fast: stream A panels
    const int bn = swzid / nbm;          // slow: B panel L2-resident

    const int tid  = threadIdx.x;
    const int wv   = tid >> 6;
    const int lane = tid & 63;
    const int wr   = wv >> 2;            // 0..1
    const int wc   = wv & 3;             // 0..3

    const unsigned short* wsA = ws + (size_t)(bm * NT) * 16384 + wv * 1024 + lane * 8;
    const unsigned short* wsB = ws + (size_t)szX + (size_t)(bn * NT) * 16384 + wv * 1024 + lane * 8;
    const int ldsWOff = wv * 1024;

    const int aBase = (lane >> 4) * 2048 + (wr * 128 + (lane & 15)) * 8;
    const int bBase = (lane >> 4) * 2048 + (wc * 64 + (lane & 15)) * 8;

    f32x4 acc[8][4] = {};

#define STAGE_A(half, tt, ss) do {                                            \
        const unsigned short* s_ = wsA + (size_t)(tt) * 16384 + (half) * 8192;\
        ASYNC16(s_,       &lds[ss][0][(half) * 8192 + ldsWOff]);              \
        ASYNC16(s_ + 512, &lds[ss][0][(half) * 8192 + ldsWOff + 512]);        \
    } while (0)
#define STAGE_B(half, tt, ss) do {                                            \
        const unsigned short* s_ = wsB + (size_t)(tt) * 16384 + (half) * 8192;\
        ASYNC16(s_,       &lds[ss][1][(half) * 8192 + ldsWOff]);              \
        ASYNC16(s_ + 512, &lds[ss][1][(half) * 8192 + ldsWOff + 512]);        \
    } while (0)
#define DSA(ss, ks, fm) (*(const bf16x8*)&lds[ss][0][(ks) * 8192 + aBase + (fm) * 128])
#define DSB(ss, ks, fn) (*(const bf16x8*)&lds[ss][1][(ks) * 8192 + bBase + (fn) * 128])
#define CLUSTER(mh, A0_, A1_, A2_, A3_, B0_, B1_, B2_, B3_) do {              \
        __builtin_amdgcn_s_setprio(1);                                        \
        acc[(mh)*4+0][0] = __builtin_amdgcn_mfma_f32_16x16x32_bf16(A0_, B0_, acc[(mh)*4+0][0], 0, 0, 0); \
        acc[(mh)*4+0][1] = __builtin_amdgcn_mfma_f32_16x16x32_bf16(A0_, B1_, acc[(mh)*4+0][1], 0, 0, 0); \
        acc[(mh)*4+0][2] = __builtin_amdgcn_mfma_f32_16x16x32_bf16(A0_, B2_, acc[(mh)*4+0][2], 0, 0, 0); \
        acc[(mh)*4+0][3] = __builtin_amdgcn_mfma_f32_16x16x32_bf16(A0_, B3_, acc[(mh)*4+0][3], 0, 0, 0); \
        acc[(mh)*4+1][0] = __builtin_amdgcn_mfma_f32_16x16x32_bf16(A1_, B0_, acc[(mh)*4+1][0], 0, 0, 0); \
        acc[(mh)*4+1][1] = __builtin_amdgcn_mfma_f32_16x16x32_bf16(A1_, B1_, acc[(mh)*4+1][1], 0, 0, 0); \
        acc[(mh)*4+1][2] = __builtin_amdgcn_mfma_f32_16x16x32_bf16(A1_, B2_, acc[(mh)*4+1][2], 0, 0, 0); \
        acc[(mh)*4+1][3] = __builtin_amdgcn_mfma_f32_16x16x32_bf16(A1_, B3_, acc[(mh)*4+1][3], 0, 0, 0); \
        acc[(mh)*4+2][0] = __builtin_amdgcn_mfma_f32_16x16x32_bf16(A2_, B0_, acc[(mh)*4+2][0], 0, 0, 0); \
        acc[(mh)*4+2][1] = __builtin_amdgcn_mfma_f32_16x16x32_bf16(A2_, B1_, acc[(mh)*4+2][1], 0, 0, 0); \
        acc[(mh)*4+2][2] = __builtin_amdgcn_mfma_f32_16x16x32_bf16(A2_, B2_, acc[(mh)*4+2][2], 0, 0, 0); \
        acc[(mh)*4+2][3] = __builtin_amdgcn_mfma_f32_16x16x32_bf16(A2_, B3_, acc[(mh)*4+2][3], 0, 0, 0); \
        acc[(mh)*4+3][0] = __builtin_amdgcn_mfma_f32_16x16x32_bf16(A3_, B0_, acc[(mh)*4+3][0], 0, 0, 0); \
        acc[(mh)*4+3][1] = __builtin_amdgcn_mfma_f32_16x16x32_bf16(A3_, B1_, acc[(mh)*4+3][1], 0, 0, 0); \
        acc[(mh)*4+3][2] = __builtin_amdgcn_mfma_f32_16x16x32_bf16(A3_, B2_, acc[(mh)*4+3][2], 0, 0, 0); \
        acc[(mh)*4+3][3] = __builtin_amdgcn_mfma_f32_16x16x32_bf16(A3_, B3_, acc[(mh)*4+3][3], 0, 0, 0); \
        __builtin_amdgcn_s_setprio(0);                                        \
    } while (0)

// One K-step: compute set ss, stage tile tn -> ss^1. vmcnt ledger/wave:
// start 8 outstanding (set ss); +2 (A0') -> 10; vmcnt(2) retires all 8 of
// ss -> publish barrier. Clusters then run barrier-free (ds_reads of
// cluster p+1 overlap cluster p's MFMA). End barrier protects set ss.
#define KSTEP(ss, tn) do {                                                    \
        STAGE_A(0, tn, (ss)^1);                                               \
        asm volatile("s_waitcnt vmcnt(2)" ::: "memory");                      \
        __builtin_amdgcn_s_barrier();                                         \
        __builtin_amdgcn_sched_barrier(0);                                    \
        bf16x8 a0 = DSA(ss,0,0), a1 = DSA(ss,0,1), a2 = DSA(ss,0,2), a3 = DSA(ss,0,3); \
        bf16x8 b0 = DSB(ss,0,0), b1 = DSB(ss,0,1), b2 = DSB(ss,0,2), b3 = DSB(ss,0,3); \
        STAGE_B(0, tn, (ss)^1);                                               \
        CLUSTER(0, a0, a1, a2, a3, b0, b1, b2, b3);                           \
        bf16x8 a4 = DSA(ss,0,4), a5 = DSA(ss,0,5), a6 = DSA(ss,0,6), a7 = DSA(ss,0,7); \
        STAGE_A(1, tn, (ss)^1);                                               \
        CLUSTER(1, a4, a5, a6, a7, b0, b1, b2, b3);                           \
        bf16x8 c0 = DSA(ss,1,0), c1 = DSA(ss,1,1), c2 = DSA(ss,1,2), c3 = DSA(ss,1,3); \
        bf16x8 d0 = DSB(ss,1,0), d1 = DSB(ss,1,1), d2 = DSB(ss,1,2), d3 = DSB(ss,1,3); \
        STAGE_B(1, tn, (ss)^1);                                               \
        CLUSTER(0, c0, c1, c2, c3, d0, d1, d2, d3);                           \
        bf16x8 c4 = DSA(ss,1,4), c5 = DSA(ss,1,5), c6 = DSA(ss,1,6), c7 = DSA(ss,1,7); \
        CLUSTER(1, c4, c5, c6, c7, d0, d1, d2, d3);                           \
        __builtin_amdgcn_s_barrier();                                         \
        __builtin_amdgcn_sched_barrier(0);                                    \
    } while (0)

    // prologue: tile 0 -> set 0 (outstanding = 8, matches steady state)
    STAGE_A(0, 0, 0);
    STAGE_B(0, 0, 0);
    STAGE_A(1, 0, 0);
    STAGE_B(1, 0, 0);

    for (int t = 0; t < NT; t += 2) {
        const int tn1 = t + 1;                          // <= NT-1
        KSTEP(0, tn1);
        const int tn2 = (t + 2 < NT) ? t + 2 : NT - 1;  // tail: redundant restage
        KSTEP(1, tn2);
    }

    // ---- epilogue: C/D col = lane&15, row = (lane>>4)*4 + r (m89-verified)
    const int crow0 = bm * 256 + wr * 128 + (lane >> 4) * 4;
    const int ccol0 = bn * 256 + wc * 64 + (lane & 15);
#pragma unroll
    for (int fm = 0; fm < 8; ++fm)
#pragma unroll
        for (int fn = 0; fn < 4; ++fn)
#pragma unroll
            for (int r = 0; r < 4; ++r)
                C[(size_t)(crow0 + fm * 16 + r) * N + (ccol0 + fn * 16)] = acc[fm][fn][r];

#undef STAGE_A
#undef STAGE_B
#undef DSA
#undef DSB
#undef CLUSTER
#undef KSTEP
}

// ---------------- fallback: Round-4 fused kernel (proven PASS, ~265 us) ----------------
__device__ inline int lds_off(int row, int slot) {
    return row * 32 + (((slot ^ ((row >> 1) & 3)) & 3) << 3);
}

__global__ __launch_bounds__(256) void gemm_bt_fused(
    const float* __restrict__ A, const float* __restrict__ B,
    float* __restrict__ C, int M, int N, int K)
{
    constexpr int BM = 128, BN = 128, BK = 32;
    __shared__ unsigned short sA[2][BM * BK];
    __shared__ unsigned short sB[2][BN * BK];

    const int nbm = M / BM, nbn = N / BN;
    const int nwg = nbm * nbn;
    const int bid = blockIdx.x;
    int swz = bid;
    if ((nwg & 7) == 0) { const int q = nwg >> 3; swz = (bid & 7) * q + (bid >> 3); }
    const int bm = swz % nbm, bn = swz / nbm;

    const int tid = threadIdx.x;
    const int srow = tid >> 1;
    const int scol = (tid & 1) * 16;
    const float* gA = A + (size_t)(bm * BM + srow) * K + scol;
    const float* gB = B + (size_t)(bn * BN + srow) * K + scol;
    const int s0  = (tid & 1) * 2;
    const int wo0 = lds_off(srow, s0);
    const int wo1 = lds_off(srow, s0 + 1);

    const int wave = tid >> 6, lane = tid & 63;
    const int wr = wave >> 1, wc = wave & 1;
    const int fr = lane & 15;
    const int slr = lane >> 4;
    int offA[4], offB[4];
#pragma unroll
    for (int i = 0; i < 4; ++i) {
        offA[i] = lds_off(wr * 64 + i * 16 + fr, slr);
        offB[i] = lds_off(wc * 64 + i * 16 + fr, slr);
    }

    f32x4 acc[4][4] = {};
    const int NT = K / BK;

    float4 va[4], vb[4];
#pragma unroll
    for (int p = 0; p < 4; ++p) {
        va[p] = *reinterpret_cast<const float4*>(gA + p * 4);
        vb[p] = *reinterpret_cast<const float4*>(gB + p * 4);
    }

    for (int t = 0; t < NT; ++t) {
        const int cur = t & 1;
        u16x8 pa0, pa1, pb0, pb1;
#pragma unroll
        for (int e = 0; e < 4; ++e) {
            pa0[e] = f2bf(va[0][e]);  pa0[4 + e] = f2bf(va[1][e]);
            pa1[e] = f2bf(va[2][e]);  pa1[4 + e] = f2bf(va[3][e]);
            pb0[e] = f2bf(vb[0][e]);  pb0[4 + e] = f2bf(vb[1][e]);
            pb1[e] = f2bf(vb[2][e]);  pb1[4 + e] = f2bf(vb[3][e]);
        }
        *reinterpret_cast<u16x8*>(&sA[cur][wo0]) = pa0;
        *reinterpret_cast<u16x8*>(&sA[cur][wo1]) = pa1;
        *reinterpret_cast<u16x8*>(&sB[cur][wo0]) = pb0;
        *reinterpret_cast<u16x8*>(&sB[cur][wo1]) = pb1;

        const int kn = (t + 1 < NT) ? (t + 1) * BK : t * BK;
#pragma unroll
        for (int p = 0; p < 4; ++p) {
            va[p] = *reinterpret_cast<const float4*>(gA + kn + p * 4);
            vb[p] = *reinterpret_cast<const float4*>(gB + kn + p * 4);
        }

        __syncthreads();

        bf16x8 a[4], b[4];
#pragma unroll
        for (int i = 0; i < 4; ++i) a[i] = *reinterpret_cast<const bf16x8*>(&sA[cur][offA[i]]);
#pragma unroll
        for (int j = 0; j < 4; ++j) b[j] = *reinterpret_cast<const bf16x8*>(&sB[cur][offB[j]]);
#pragma unroll
        for (int i = 0; i < 4; ++i)
#pragma unroll
            for (int j = 0; j < 4; ++j)
                acc[i][j] = __builtin_amdgcn_mfma_f32_16x16x32_bf16(a[i], b[j], acc[i][j], 0, 0, 0);
    }

    const int crow0 = bm * BM + wr * 64 + (lane >> 4) * 4;
    const int ccol0 = bn * BN + wc * 64 + fr;
#pragma unroll
    for (int i = 0; i < 4; ++i)
#pragma unroll
        for (int j = 0; j < 4; ++j)
#pragma unroll
            for (int r = 0; r < 4; ++r)
                C[(size_t)(crow0 + i * 16 + r) * N + (ccol0 + j * 16)] = acc[i][j][r];
}

extern "C" void kernel_launch(void* const* d_in, const int* in_sizes, int n_in,
                              void* d_out, int out_size, void* d_ws, size_t ws_size,
                              hipStream_t stream) {
    int K = 4096;
    int M = in_sizes[0] / K;   // 2048
    int N = in_sizes[1] / K;   // 8192

    const float* x = (const float*)d_in[0];
    const float* w = (const float*)d_in[1];
    float* out     = (float*)d_out;
    unsigned short* wsp = (unsigned short*)d_ws;

    const size_t szX = (size_t)in_sizes[0], szW = (size_t)in_sizes[1];
    const size_t cntOff = (((szX + szW) * 2) + 255) & ~(size_t)255;
    const size_t need = cntOff + 256;
    unsigned int* cnt = (unsigned int*)((char*)d_ws + cntOff);

    const int nwg2 = (M >> 8) * (N >> 8);   // 256 = 1 block/CU

    bool geom_ok = (M % 256 == 0) && (N % 256 == 0) && (K % 128 == 0) &&
                   ((nwg2 & 7) == 0);
    int maxB = 0;
    hipError_t oe = hipOccupancyMaxActiveBlocksPerMultiprocessor(&maxB, persist_cvt_gemm, 512, 0);
    const bool pers_ok = geom_ok && (oe == hipSuccess) && (ws_size >= need) &&
                         ((long long)maxB * 256 >= (long long)nwg2);  // co-residency

    if (pers_ok) {
        reset_cnt<<<dim3(1), dim3(1), 0, stream>>>(cnt);
        persist_cvt_gemm<<<dim3(nwg2), dim3(512), 0, stream>>>(x, w, wsp, cnt, out, M, N, K);
        return;
    }
    const int nwg = (M / 128) * (N / 128);
    gemm_bt_fused<<<dim3(nwg), dim3(256), 0, stream>>>(x, w, out, M, N, K);
}

// Round 13
// 264.886 us; speedup vs baseline: 1.0038x; 1.0038x over previous
//
#include <hip/hip_runtime.h>
#include <hip/hip_bf16.h>
#include <cstdint>

// out[M,N] = x[M,K] @ weight[N,K]^T, fp32 device buffers.
// TWO plain (graph-capturable) dispatches:
//   1) reset_cnt<<<1,1>>>
//   2) persist_cvt_gemm<<<256,512>>> (1 block/CU):
//      phase 1: COALESCED LDS-staged cvt fp32->bf16 into d_ws
//               (R12's dest-linear walk read source at 16KB stride ->
//                uncoalesced; now: coalesced read -> LDS fragment-order
//                -> coalesced linear write)
//      hand-rolled agent-scope atomic grid barrier
//      phase 2: 256x256 GEMM, BK=64, 8 waves, publish-once vmcnt(2) K-step
//               (byte-identical to R12's validated GEMM).

typedef __bf16 bf16x8 __attribute__((ext_vector_type(8)));
typedef float f32x4 __attribute__((ext_vector_type(4)));
typedef unsigned short u16x8 __attribute__((ext_vector_type(8)));

#define GAS __attribute__((address_space(1)))
#define LAS __attribute__((address_space(3)))
#define ASYNC16(gsrc, ldst)                                                  \
    __builtin_amdgcn_global_load_lds((GAS uint32_t*)(const void*)(gsrc),     \
                                     (LAS uint32_t*)(ldst), 16, 0, 0)

__device__ inline unsigned short f2bf(float f) {
    __hip_bfloat16 h = __float2bfloat16(f);  // RNE
    return *reinterpret_cast<unsigned short*>(&h);
}

__global__ void reset_cnt(unsigned int* cnt) {
    atomicExch(cnt, 0u);
}

__global__ __launch_bounds__(512, 1) void persist_cvt_gemm(
    const float* __restrict__ A32,       // x      [M,K]
    const float* __restrict__ B32,       // weight [N,K]
    unsigned short* __restrict__ ws,     // bf16 tiled [szX | szW]
    unsigned int* __restrict__ cnt,      // grid-barrier counter (reset to 0)
    float* __restrict__ C,               // out    [M,N]
    int M, int N, int K)
{
    const int NT  = K >> 6;              // 64 K-steps
    const int szX = M * K;
    const int szW = N * K;

    __shared__ unsigned short lds[2][2][16384];  // 128 KB (GEMM dbuf; 32 KB reused by cvt)

    const int tid = threadIdx.x;

    // ================= phase 1: coalesced LDS-staged cvt =================
    // chunk = one (tile256, kt64): [256 rows][64 k] bf16 = 32 KB, stored
    // fragment-ordered: off = ks*8192 + g*2048 + row*8  (k_local = ks*32+g*8).
    {
        const int CH_A = (M >> 8) * NT;              // A chunks
        const int CH_T = CH_A + (N >> 8) * NT;       // total chunks
        unsigned short* cbuf = &lds[0][0][0];        // 32 KB scratch
        for (int cid = blockIdx.x; cid < CH_T; cid += gridDim.x) {
            int cl; const float* base; unsigned short* dstc;
            if (cid < CH_A) { cl = cid;        base = A32; dstc = ws + ((size_t)cl << 14); }
            else            { cl = cid - CH_A; base = B32; dstc = ws + (size_t)szX + ((size_t)cl << 14); }
            const int tile = cl >> 6, kt = cl & 63;
            const float* srcc = base + ((size_t)(tile << 8)) * K + (kt << 6);
            // coalesced read: 8 threads x 32B cover one row's 256B; 64 rows/pass
#pragma unroll
            for (int p = 0; p < 4; ++p) {
                const int row = (p << 6) + (tid >> 3);
                const int kg  = tid & 7;                      // 8-float group
                const float* s = srcc + (size_t)row * K + (kg << 3);
                float4 v0 = *reinterpret_cast<const float4*>(s);
                float4 v1 = *reinterpret_cast<const float4*>(s + 4);
                u16x8 o;
                o[0] = f2bf(v0.x); o[1] = f2bf(v0.y); o[2] = f2bf(v0.z); o[3] = f2bf(v0.w);
                o[4] = f2bf(v1.x); o[5] = f2bf(v1.y); o[6] = f2bf(v1.z); o[7] = f2bf(v1.w);
                *reinterpret_cast<u16x8*>(
                    &cbuf[(kg >> 2) * 8192 + (kg & 3) * 2048 + row * 8]) = o;
            }
            __syncthreads();
            // coalesced linear copy LDS -> ws (16B/lane)
#pragma unroll
            for (int p = 0; p < 4; ++p) {
                const int off = (p << 12) + (tid << 3);
                *reinterpret_cast<u16x8*>(dstc + off) =
                    *reinterpret_cast<const u16x8*>(&cbuf[off]);
            }
            __syncthreads();
        }
    }

    // ============ grid barrier (agent scope) ============
    {
        __syncthreads();
        if (tid == 0) {
            __threadfence();
            __hip_atomic_fetch_add(cnt, 1u, __ATOMIC_ACQ_REL, __HIP_MEMORY_SCOPE_AGENT);
            while (__hip_atomic_load(cnt, __ATOMIC_ACQUIRE, __HIP_MEMORY_SCOPE_AGENT)
                   < gridDim.x) {
                __builtin_amdgcn_s_sleep(2);
            }
        }
        __syncthreads();
    }
    asm volatile("s_waitcnt vmcnt(0)" ::: "memory");

    // ================= phase 2: GEMM (R12-identical) =================
    const int nbm = M >> 8;              // 8
    const int nbn = N >> 8;              // 32
    const int bid = blockIdx.x;
    const int swzid = (bid & 7) * ((nbm * nbn) >> 3) + (bid >> 3);
    const int bm = swzid % nbm;
    const int bn = swzid / nbm;

    const int wv   = tid >> 6;
    const int lane = tid & 63;
    const int wr   = wv >> 2;
    const int wc   = wv & 3;

    const unsigned short* wsA = ws + (size_t)(bm * NT) * 16384 + wv * 1024 + lane * 8;
    const unsigned short* wsB = ws + (size_t)szX + (size_t)(bn * NT) * 16384 + wv * 1024 + lane * 8;
    const int ldsWOff = wv * 1024;

    const int aBase = (lane >> 4) * 2048 + (wr * 128 + (lane & 15)) * 8;
    const int bBase = (lane >> 4) * 2048 + (wc * 64 + (lane & 15)) * 8;

    f32x4 acc[8][4] = {};

#define STAGE_A(half, tt, ss) do {                                            \
        const unsigned short* s_ = wsA + (size_t)(tt) * 16384 + (half) * 8192;\
        ASYNC16(s_,       &lds[ss][0][(half) * 8192 + ldsWOff]);              \
        ASYNC16(s_ + 512, &lds[ss][0][(half) * 8192 + ldsWOff + 512]);        \
    } while (0)
#define STAGE_B(half, tt, ss) do {                                            \
        const unsigned short* s_ = wsB + (size_t)(tt) * 16384 + (half) * 8192;\
        ASYNC16(s_,       &lds[ss][1][(half) * 8192 + ldsWOff]);              \
        ASYNC16(s_ + 512, &lds[ss][1][(half) * 8192 + ldsWOff + 512]);        \
    } while (0)
#define DSA(ss, ks, fm) (*(const bf16x8*)&lds[ss][0][(ks) * 8192 + aBase + (fm) * 128])
#define DSB(ss, ks, fn) (*(const bf16x8*)&lds[ss][1][(ks) * 8192 + bBase + (fn) * 128])
#define CLUSTER(mh, A0_, A1_, A2_, A3_, B0_, B1_, B2_, B3_) do {              \
        __builtin_amdgcn_s_setprio(1);                                        \
        acc[(mh)*4+0][0] = __builtin_amdgcn_mfma_f32_16x16x32_bf16(A0_, B0_, acc[(mh)*4+0][0], 0, 0, 0); \
        acc[(mh)*4+0][1] = __builtin_amdgcn_mfma_f32_16x16x32_bf16(A0_, B1_, acc[(mh)*4+0][1], 0, 0, 0); \
        acc[(mh)*4+0][2] = __builtin_amdgcn_mfma_f32_16x16x32_bf16(A0_, B2_, acc[(mh)*4+0][2], 0, 0, 0); \
        acc[(mh)*4+0][3] = __builtin_amdgcn_mfma_f32_16x16x32_bf16(A0_, B3_, acc[(mh)*4+0][3], 0, 0, 0); \
        acc[(mh)*4+1][0] = __builtin_amdgcn_mfma_f32_16x16x32_bf16(A1_, B0_, acc[(mh)*4+1][0], 0, 0, 0); \
        acc[(mh)*4+1][1] = __builtin_amdgcn_mfma_f32_16x16x32_bf16(A1_, B1_, acc[(mh)*4+1][1], 0, 0, 0); \
        acc[(mh)*4+1][2] = __builtin_amdgcn_mfma_f32_16x16x32_bf16(A1_, B2_, acc[(mh)*4+1][2], 0, 0, 0); \
        acc[(mh)*4+1][3] = __builtin_amdgcn_mfma_f32_16x16x32_bf16(A1_, B3_, acc[(mh)*4+1][3], 0, 0, 0); \
        acc[(mh)*4+2][0] = __builtin_amdgcn_mfma_f32_16x16x32_bf16(A2_, B0_, acc[(mh)*4+2][0], 0, 0, 0); \
        acc[(mh)*4+2][1] = __builtin_amdgcn_mfma_f32_16x16x32_bf16(A2_, B1_, acc[(mh)*4+2][1], 0, 0, 0); \
        acc[(mh)*4+2][2] = __builtin_amdgcn_mfma_f32_16x16x32_bf16(A2_, B2_, acc[(mh)*4+2][2], 0, 0, 0); \
        acc[(mh)*4+2][3] = __builtin_amdgcn_mfma_f32_16x16x32_bf16(A2_, B3_, acc[(mh)*4+2][3], 0, 0, 0); \
        acc[(mh)*4+3][0] = __builtin_amdgcn_mfma_f32_16x16x32_bf16(A3_, B0_, acc[(mh)*4+3][0], 0, 0, 0); \
        acc[(mh)*4+3][1] = __builtin_amdgcn_mfma_f32_16x16x32_bf16(A3_, B1_, acc[(mh)*4+3][1], 0, 0, 0); \
        acc[(mh)*4+3][2] = __builtin_amdgcn_mfma_f32_16x16x32_bf16(A3_, B2_, acc[(mh)*4+3][2], 0, 0, 0); \
        acc[(mh)*4+3][3] = __builtin_amdgcn_mfma_f32_16x16x32_bf16(A3_, B3_, acc[(mh)*4+3][3], 0, 0, 0); \
        __builtin_amdgcn_s_setprio(0);                                        \
    } while (0)
#define KSTEP(ss, tn) do {                                                    \
        STAGE_A(0, tn, (ss)^1);                                               \
        asm volatile("s_waitcnt vmcnt(2)" ::: "memory");                      \
        __builtin_amdgcn_s_barrier();                                         \
        __builtin_amdgcn_sched_barrier(0);                                    \
        bf16x8 a0 = DSA(ss,0,0), a1 = DSA(ss,0,1), a2 = DSA(ss,0,2), a3 = DSA(ss,0,3); \
        bf16x8 b0 = DSB(ss,0,0), b1 = DSB(ss,0,1), b2 = DSB(ss,0,2), b3 = DSB(ss,0,3); \
        STAGE_B(0, tn, (ss)^1);                                               \
        CLUSTER(0, a0, a1, a2, a3, b0, b1, b2, b3);                           \
        bf16x8 a4 = DSA(ss,0,4), a5 = DSA(ss,0,5), a6 = DSA(ss,0,6), a7 = DSA(ss,0,7); \
        STAGE_A(1, tn, (ss)^1);                                               \
        CLUSTER(1, a4, a5, a6, a7, b0, b1, b2, b3);                           \
        bf16x8 c0 = DSA(ss,1,0), c1 = DSA(ss,1,1), c2 = DSA(ss,1,2), c3 = DSA(ss,1,3); \
        bf16x8 d0 = DSB(ss,1,0), d1 = DSB(ss,1,1), d2 = DSB(ss,1,2), d3 = DSB(ss,1,3); \
        STAGE_B(1, tn, (ss)^1);                                               \
        CLUSTER(0, c0, c1, c2, c3, d0, d1, d2, d3);                           \
        bf16x8 c4 = DSA(ss,1,4), c5 = DSA(ss,1,5), c6 = DSA(ss,1,6), c7 = DSA(ss,1,7); \
        CLUSTER(1, c4, c5, c6, c7, d0, d1, d2, d3);                           \
        __builtin_amdgcn_s_barrier();                                         \
        __builtin_amdgcn_sched_barrier(0);                                    \
    } while (0)

    STAGE_A(0, 0, 0);
    STAGE_B(0, 0, 0);
    STAGE_A(1, 0, 0);
    STAGE_B(1, 0, 0);

    for (int t = 0; t < NT; t += 2) {
        const int tn1 = t + 1;
        KSTEP(0, tn1);
        const int tn2 = (t + 2 < NT) ? t + 2 : NT - 1;
        KSTEP(1, tn2);
    }

    const int crow0 = bm * 256 + wr * 128 + (lane >> 4) * 4;
    const int ccol0 = bn * 256 + wc * 64 + (lane & 15);
#pragma unroll
    for (int fm = 0; fm < 8; ++fm)
#pragma unroll
        for (int fn = 0; fn < 4; ++fn)
#pragma unroll
            for (int r = 0; r < 4; ++r)
                C[(size_t)(crow0 + fm * 16 + r) * N + (ccol0 + fn * 16)] = acc[fm][fn][r];

#undef STAGE_A
#undef STAGE_B
#undef DSA
#undef DSB
#undef CLUSTER
#undef KSTEP
}

// ---------------- fallback: Round-4 fused kernel (proven PASS, ~265 us) ----------------
__device__ inline int lds_off(int row, int slot) {
    return row * 32 + (((slot ^ ((row >> 1) & 3)) & 3) << 3);
}

__global__ __launch_bounds__(256) void gemm_bt_fused(
    const float* __restrict__ A, const float* __restrict__ B,
    float* __restrict__ C, int M, int N, int K)
{
    constexpr int BM = 128, BN = 128, BK = 32;
    __shared__ unsigned short sA[2][BM * BK];
    __shared__ unsigned short sB[2][BN * BK];

    const int nbm = M / BM, nbn = N / BN;
    const int nwg = nbm * nbn;
    const int bid = blockIdx.x;
    int swz = bid;
    if ((nwg & 7) == 0) { const int q = nwg >> 3; swz = (bid & 7) * q + (bid >> 3); }
    const int bm = swz % nbm, bn = swz / nbm;

    const int tid = threadIdx.x;
    const int srow = tid >> 1;
    const int scol = (tid & 1) * 16;
    const float* gA = A + (size_t)(bm * BM + srow) * K + scol;
    const float* gB = B + (size_t)(bn * BN + srow) * K + scol;
    const int s0  = (tid & 1) * 2;
    const int wo0 = lds_off(srow, s0);
    const int wo1 = lds_off(srow, s0 + 1);

    const int wave = tid >> 6, lane = tid & 63;
    const int wr = wave >> 1, wc = wave & 1;
    const int fr = lane & 15;
    const int slr = lane >> 4;
    int offA[4], offB[4];
#pragma unroll
    for (int i = 0; i < 4; ++i) {
        offA[i] = lds_off(wr * 64 + i * 16 + fr, slr);
        offB[i] = lds_off(wc * 64 + i * 16 + fr, slr);
    }

    f32x4 acc[4][4] = {};
    const int NT = K / BK;

    float4 va[4], vb[4];
#pragma unroll
    for (int p = 0; p < 4; ++p) {
        va[p] = *reinterpret_cast<const float4*>(gA + p * 4);
        vb[p] = *reinterpret_cast<const float4*>(gB + p * 4);
    }

    for (int t = 0; t < NT; ++t) {
        const int cur = t & 1;
        u16x8 pa0, pa1, pb0, pb1;
#pragma unroll
        for (int e = 0; e < 4; ++e) {
            pa0[e] = f2bf(va[0][e]);  pa0[4 + e] = f2bf(va[1][e]);
            pa1[e] = f2bf(va[2][e]);  pa1[4 + e] = f2bf(va[3][e]);
            pb0[e] = f2bf(vb[0][e]);  pb0[4 + e] = f2bf(vb[1][e]);
            pb1[e] = f2bf(vb[2][e]);  pb1[4 + e] = f2bf(vb[3][e]);
        }
        *reinterpret_cast<u16x8*>(&sA[cur][wo0]) = pa0;
        *reinterpret_cast<u16x8*>(&sA[cur][wo1]) = pa1;
        *reinterpret_cast<u16x8*>(&sB[cur][wo0]) = pb0;
        *reinterpret_cast<u16x8*>(&sB[cur][wo1]) = pb1;

        const int kn = (t + 1 < NT) ? (t + 1) * BK : t * BK;
#pragma unroll
        for (int p = 0; p < 4; ++p) {
            va[p] = *reinterpret_cast<const float4*>(gA + kn + p * 4);
            vb[p] = *reinterpret_cast<const float4*>(gB + kn + p * 4);
        }

        __syncthreads();

        bf16x8 a[4], b[4];
#pragma unroll
        for (int i = 0; i < 4; ++i) a[i] = *reinterpret_cast<const bf16x8*>(&sA[cur][offA[i]]);
#pragma unroll
        for (int j = 0; j < 4; ++j) b[j] = *reinterpret_cast<const bf16x8*>(&sB[cur][offB[j]]);
#pragma unroll
        for (int i = 0; i < 4; ++i)
#pragma unroll
            for (int j = 0; j < 4; ++j)
                acc[i][j] = __builtin_amdgcn_mfma_f32_16x16x32_bf16(a[i], b[j], acc[i][j], 0, 0, 0);
    }

    const int crow0 = bm * BM + wr * 64 + (lane >> 4) * 4;
    const int ccol0 = bn * BN + wc * 64 + fr;
#pragma unroll
    for (int i = 0; i < 4; ++i)
#pragma unroll
        for (int j = 0; j < 4; ++j)
#pragma unroll
            for (int r = 0; r < 4; ++r)
                C[(size_t)(crow0 + i * 16 + r) * N + (ccol0 + j * 16)] = acc[i][j][r];
}

extern "C" void kernel_launch(void* const* d_in, const int* in_sizes, int n_in,
                              void* d_out, int out_size, void* d_ws, size_t ws_size,
                              hipStream_t stream) {
    int K = 4096;
    int M = in_sizes[0] / K;   // 2048
    int N = in_sizes[1] / K;   // 8192

    const float* x = (const float*)d_in[0];
    const float* w = (const float*)d_in[1];
    float* out     = (float*)d_out;
    unsigned short* wsp = (unsigned short*)d_ws;

    const size_t szX = (size_t)in_sizes[0], szW = (size_t)in_sizes[1];
    const size_t cntOff = (((szX + szW) * 2) + 255) & ~(size_t)255;
    const size_t need = cntOff + 256;
    unsigned int* cnt = (unsigned int*)((char*)d_ws + cntOff);

    const int nwg2 = (M >> 8) * (N >> 8);   // 256 = 1 block/CU

    bool geom_ok = (M % 256 == 0) && (N % 256 == 0) && (K % 64 == 0) &&
                   ((nwg2 & 7) == 0);
    int maxB = 0;
    hipError_t oe = hipOccupancyMaxActiveBlocksPerMultiprocessor(&maxB, persist_cvt_gemm, 512, 0);
    const bool pers_ok = geom_ok && (oe == hipSuccess) && (ws_size >= need) &&
                         ((long long)maxB * 256 >= (long long)nwg2);

    if (pers_ok) {
        reset_cnt<<<dim3(1), dim3(1), 0, stream>>>(cnt);
        persist_cvt_gemm<<<dim3(nwg2), dim3(512), 0, stream>>>(x, w, wsp, cnt, out, M, N, K);
        return;
    }
    const int nwg = (M / 128) * (N / 128);
    gemm_bt_fused<<<dim3(nwg), dim3(256), 0, stream>>>(x, w, out, M, N, K);
}

// Round 14
// 205.562 us; speedup vs baseline: 1.2935x; 1.2886x over previous
//
#include <hip/hip_runtime.h>
#include <hip/hip_bf16.h>
#include <cstdint>

// out[M,N] = x[M,K] @ weight[N,K]^T, fp32 device buffers.
// TWO plain (graph-capturable) dispatches, NO runtime API in path selection:
//   1) reset_cnt<<<1,1>>>  (ws is poisoned 0xAA before timing -> must zero cnt)
//   2) persist_cvt_gemm<<<256,512>>> (1 block/CU, statically co-resident):
//      phase 1: coalesced LDS-staged cvt fp32->bf16 into d_ws
//      agent-scope atomic grid barrier
//      phase 2: 256x256 GEMM, BK=64, 8 waves, publish-once vmcnt(2) K-step
// R14 change vs R13: removed hipOccupancyMaxActiveBlocksPerMultiprocessor and
// the fallback branch from the launch path. Hypothesis: that query behaves
// differently inside hipGraph capture -> pers_ok flipped false -> every timed
// run since R4 captured the 265-us fallback (explains timed==265.x constancy
// while profiled kernels varied 243-374 us). Kernel body = R13, validated 2x.

typedef __bf16 bf16x8 __attribute__((ext_vector_type(8)));
typedef float f32x4 __attribute__((ext_vector_type(4)));
typedef unsigned short u16x8 __attribute__((ext_vector_type(8)));

#define GAS __attribute__((address_space(1)))
#define LAS __attribute__((address_space(3)))
#define ASYNC16(gsrc, ldst)                                                  \
    __builtin_amdgcn_global_load_lds((GAS uint32_t*)(const void*)(gsrc),     \
                                     (LAS uint32_t*)(ldst), 16, 0, 0)

__device__ inline unsigned short f2bf(float f) {
    __hip_bfloat16 h = __float2bfloat16(f);  // RNE
    return *reinterpret_cast<unsigned short*>(&h);
}

__global__ void reset_cnt(unsigned int* cnt) {
    atomicExch(cnt, 0u);
}

__global__ __launch_bounds__(512, 1) void persist_cvt_gemm(
    const float* __restrict__ A32,       // x      [M,K]
    const float* __restrict__ B32,       // weight [N,K]
    unsigned short* __restrict__ ws,     // bf16 tiled [szX | szW]
    unsigned int* __restrict__ cnt,      // grid-barrier counter (reset to 0)
    float* __restrict__ C,               // out    [M,N]
    int M, int N, int K)
{
    const int NT  = K >> 6;              // 64 K-steps
    const int szX = M * K;
    const int szW = N * K;

    __shared__ unsigned short lds[2][2][16384];  // 128 KB (GEMM dbuf; 32 KB reused by cvt)

    const int tid = threadIdx.x;

    // ================= phase 1: coalesced LDS-staged cvt =================
    // chunk = one (tile256, kt64): [256 rows][64 k] bf16 = 32 KB, stored
    // fragment-ordered: off = ks*8192 + g*2048 + row*8  (k_local = ks*32+g*8).
    {
        const int CH_A = (M >> 8) * NT;              // A chunks
        const int CH_T = CH_A + (N >> 8) * NT;       // total chunks
        unsigned short* cbuf = &lds[0][0][0];        // 32 KB scratch
        for (int cid = blockIdx.x; cid < CH_T; cid += gridDim.x) {
            int cl; const float* base; unsigned short* dstc;
            if (cid < CH_A) { cl = cid;        base = A32; dstc = ws + ((size_t)cl << 14); }
            else            { cl = cid - CH_A; base = B32; dstc = ws + (size_t)szX + ((size_t)cl << 14); }
            const int tile = cl >> 6, kt = cl & 63;
            const float* srcc = base + ((size_t)(tile << 8)) * K + (kt << 6);
            // coalesced read: 8 threads x 32B cover one row's 256B; 64 rows/pass
#pragma unroll
            for (int p = 0; p < 4; ++p) {
                const int row = (p << 6) + (tid >> 3);
                const int kg  = tid & 7;                      // 8-float group
                const float* s = srcc + (size_t)row * K + (kg << 3);
                float4 v0 = *reinterpret_cast<const float4*>(s);
                float4 v1 = *reinterpret_cast<const float4*>(s + 4);
                u16x8 o;
                o[0] = f2bf(v0.x); o[1] = f2bf(v0.y); o[2] = f2bf(v0.z); o[3] = f2bf(v0.w);
                o[4] = f2bf(v1.x); o[5] = f2bf(v1.y); o[6] = f2bf(v1.z); o[7] = f2bf(v1.w);
                *reinterpret_cast<u16x8*>(
                    &cbuf[(kg >> 2) * 8192 + (kg & 3) * 2048 + row * 8]) = o;
            }
            __syncthreads();
            // coalesced linear copy LDS -> ws (16B/lane)
#pragma unroll
            for (int p = 0; p < 4; ++p) {
                const int off = (p << 12) + (tid << 3);
                *reinterpret_cast<u16x8*>(dstc + off) =
                    *reinterpret_cast<const u16x8*>(&cbuf[off]);
            }
            __syncthreads();
        }
    }

    // ============ grid barrier (agent scope) ============
    {
        __syncthreads();
        if (tid == 0) {
            __threadfence();
            __hip_atomic_fetch_add(cnt, 1u, __ATOMIC_ACQ_REL, __HIP_MEMORY_SCOPE_AGENT);
            while (__hip_atomic_load(cnt, __ATOMIC_ACQUIRE, __HIP_MEMORY_SCOPE_AGENT)
                   < gridDim.x) {
                __builtin_amdgcn_s_sleep(2);
            }
        }
        __syncthreads();
    }
    asm volatile("s_waitcnt vmcnt(0)" ::: "memory");

    // ================= phase 2: GEMM (R12/R13-identical) =================
    const int nbm = M >> 8;              // 8
    const int nbn = N >> 8;              // 32
    const int bid = blockIdx.x;
    const int swzid = (bid & 7) * ((nbm * nbn) >> 3) + (bid >> 3);
    const int bm = swzid % nbm;
    const int bn = swzid / nbm;

    const int wv   = tid >> 6;
    const int lane = tid & 63;
    const int wr   = wv >> 2;
    const int wc   = wv & 3;

    const unsigned short* wsA = ws + (size_t)(bm * NT) * 16384 + wv * 1024 + lane * 8;
    const unsigned short* wsB = ws + (size_t)szX + (size_t)(bn * NT) * 16384 + wv * 1024 + lane * 8;
    const int ldsWOff = wv * 1024;

    const int aBase = (lane >> 4) * 2048 + (wr * 128 + (lane & 15)) * 8;
    const int bBase = (lane >> 4) * 2048 + (wc * 64 + (lane & 15)) * 8;

    f32x4 acc[8][4] = {};

#define STAGE_A(half, tt, ss) do {                                            \
        const unsigned short* s_ = wsA + (size_t)(tt) * 16384 + (half) * 8192;\
        ASYNC16(s_,       &lds[ss][0][(half) * 8192 + ldsWOff]);              \
        ASYNC16(s_ + 512, &lds[ss][0][(half) * 8192 + ldsWOff + 512]);        \
    } while (0)
#define STAGE_B(half, tt, ss) do {                                            \
        const unsigned short* s_ = wsB + (size_t)(tt) * 16384 + (half) * 8192;\
        ASYNC16(s_,       &lds[ss][1][(half) * 8192 + ldsWOff]);              \
        ASYNC16(s_ + 512, &lds[ss][1][(half) * 8192 + ldsWOff + 512]);        \
    } while (0)
#define DSA(ss, ks, fm) (*(const bf16x8*)&lds[ss][0][(ks) * 8192 + aBase + (fm) * 128])
#define DSB(ss, ks, fn) (*(const bf16x8*)&lds[ss][1][(ks) * 8192 + bBase + (fn) * 128])
#define CLUSTER(mh, A0_, A1_, A2_, A3_, B0_, B1_, B2_, B3_) do {              \
        __builtin_amdgcn_s_setprio(1);                                        \
        acc[(mh)*4+0][0] = __builtin_amdgcn_mfma_f32_16x16x32_bf16(A0_, B0_, acc[(mh)*4+0][0], 0, 0, 0); \
        acc[(mh)*4+0][1] = __builtin_amdgcn_mfma_f32_16x16x32_bf16(A0_, B1_, acc[(mh)*4+0][1], 0, 0, 0); \
        acc[(mh)*4+0][2] = __builtin_amdgcn_mfma_f32_16x16x32_bf16(A0_, B2_, acc[(mh)*4+0][2], 0, 0, 0); \
        acc[(mh)*4+0][3] = __builtin_amdgcn_mfma_f32_16x16x32_bf16(A0_, B3_, acc[(mh)*4+0][3], 0, 0, 0); \
        acc[(mh)*4+1][0] = __builtin_amdgcn_mfma_f32_16x16x32_bf16(A1_, B0_, acc[(mh)*4+1][0], 0, 0, 0); \
        acc[(mh)*4+1][1] = __builtin_amdgcn_mfma_f32_16x16x32_bf16(A1_, B1_, acc[(mh)*4+1][1], 0, 0, 0); \
        acc[(mh)*4+1][2] = __builtin_amdgcn_mfma_f32_16x16x32_bf16(A1_, B2_, acc[(mh)*4+1][2], 0, 0, 0); \
        acc[(mh)*4+1][3] = __builtin_amdgcn_mfma_f32_16x16x32_bf16(A1_, B3_, acc[(mh)*4+1][3], 0, 0, 0); \
        acc[(mh)*4+2][0] = __builtin_amdgcn_mfma_f32_16x16x32_bf16(A2_, B0_, acc[(mh)*4+2][0], 0, 0, 0); \
        acc[(mh)*4+2][1] = __builtin_amdgcn_mfma_f32_16x16x32_bf16(A2_, B1_, acc[(mh)*4+2][1], 0, 0, 0); \
        acc[(mh)*4+2][2] = __builtin_amdgcn_mfma_f32_16x16x32_bf16(A2_, B2_, acc[(mh)*4+2][2], 0, 0, 0); \
        acc[(mh)*4+2][3] = __builtin_amdgcn_mfma_f32_16x16x32_bf16(A2_, B3_, acc[(mh)*4+2][3], 0, 0, 0); \
        acc[(mh)*4+3][0] = __builtin_amdgcn_mfma_f32_16x16x32_bf16(A3_, B0_, acc[(mh)*4+3][0], 0, 0, 0); \
        acc[(mh)*4+3][1] = __builtin_amdgcn_mfma_f32_16x16x32_bf16(A3_, B1_, acc[(mh)*4+3][1], 0, 0, 0); \
        acc[(mh)*4+3][2] = __builtin_amdgcn_mfma_f32_16x16x32_bf16(A3_, B2_, acc[(mh)*4+3][2], 0, 0, 0); \
        acc[(mh)*4+3][3] = __builtin_amdgcn_mfma_f32_16x16x32_bf16(A3_, B3_, acc[(mh)*4+3][3], 0, 0, 0); \
        __builtin_amdgcn_s_setprio(0);                                        \
    } while (0)
#define KSTEP(ss, tn) do {                                                    \
        STAGE_A(0, tn, (ss)^1);                                               \
        asm volatile("s_waitcnt vmcnt(2)" ::: "memory");                      \
        __builtin_amdgcn_s_barrier();                                         \
        __builtin_amdgcn_sched_barrier(0);                                    \
        bf16x8 a0 = DSA(ss,0,0), a1 = DSA(ss,0,1), a2 = DSA(ss,0,2), a3 = DSA(ss,0,3); \
        bf16x8 b0 = DSB(ss,0,0), b1 = DSB(ss,0,1), b2 = DSB(ss,0,2), b3 = DSB(ss,0,3); \
        STAGE_B(0, tn, (ss)^1);                                               \
        CLUSTER(0, a0, a1, a2, a3, b0, b1, b2, b3);                           \
        bf16x8 a4 = DSA(ss,0,4), a5 = DSA(ss,0,5), a6 = DSA(ss,0,6), a7 = DSA(ss,0,7); \
        STAGE_A(1, tn, (ss)^1);                                               \
        CLUSTER(1, a4, a5, a6, a7, b0, b1, b2, b3);                           \
        bf16x8 c0 = DSA(ss,1,0), c1 = DSA(ss,1,1), c2 = DSA(ss,1,2), c3 = DSA(ss,1,3); \
        bf16x8 d0 = DSB(ss,1,0), d1 = DSB(ss,1,1), d2 = DSB(ss,1,2), d3 = DSB(ss,1,3); \
        STAGE_B(1, tn, (ss)^1);                                               \
        CLUSTER(0, c0, c1, c2, c3, d0, d1, d2, d3);                           \
        bf16x8 c4 = DSA(ss,1,4), c5 = DSA(ss,1,5), c6 = DSA(ss,1,6), c7 = DSA(ss,1,7); \
        CLUSTER(1, c4, c5, c6, c7, d0, d1, d2, d3);                           \
        __builtin_amdgcn_s_barrier();                                         \
        __builtin_amdgcn_sched_barrier(0);                                    \
    } while (0)

    STAGE_A(0, 0, 0);
    STAGE_B(0, 0, 0);
    STAGE_A(1, 0, 0);
    STAGE_B(1, 0, 0);

    for (int t = 0; t < NT; t += 2) {
        const int tn1 = t + 1;
        KSTEP(0, tn1);
        const int tn2 = (t + 2 < NT) ? t + 2 : NT - 1;
        KSTEP(1, tn2);
    }

    const int crow0 = bm * 256 + wr * 128 + (lane >> 4) * 4;
    const int ccol0 = bn * 256 + wc * 64 + (lane & 15);
#pragma unroll
    for (int fm = 0; fm < 8; ++fm)
#pragma unroll
        for (int fn = 0; fn < 4; ++fn)
#pragma unroll
            for (int r = 0; r < 4; ++r)
                C[(size_t)(crow0 + fm * 16 + r) * N + (ccol0 + fn * 16)] = acc[fm][fn][r];

#undef STAGE_A
#undef STAGE_B
#undef DSA
#undef DSB
#undef CLUSTER
#undef KSTEP
}

// ---------------- fallback (geometry mismatch only; never taken at 2048x8192x4096) ----------------
__device__ inline int lds_off(int row, int slot) {
    return row * 32 + (((slot ^ ((row >> 1) & 3)) & 3) << 3);
}

__global__ __launch_bounds__(256) void gemm_bt_fused(
    const float* __restrict__ A, const float* __restrict__ B,
    float* __restrict__ C, int M, int N, int K)
{
    constexpr int BM = 128, BN = 128, BK = 32;
    __shared__ unsigned short sA[2][BM * BK];
    __shared__ unsigned short sB[2][BN * BK];

    const int nbm = M / BM, nbn = N / BN;
    const int nwg = nbm * nbn;
    const int bid = blockIdx.x;
    int swz = bid;
    if ((nwg & 7) == 0) { const int q = nwg >> 3; swz = (bid & 7) * q + (bid >> 3); }
    const int bm = swz % nbm, bn = swz / nbm;

    const int tid = threadIdx.x;
    const int srow = tid >> 1;
    const int scol = (tid & 1) * 16;
    const float* gA = A + (size_t)(bm * BM + srow) * K + scol;
    const float* gB = B + (size_t)(bn * BN + srow) * K + scol;
    const int s0  = (tid & 1) * 2;
    const int wo0 = lds_off(srow, s0);
    const int wo1 = lds_off(srow, s0 + 1);

    const int wave = tid >> 6, lane = tid & 63;
    const int wr = wave >> 1, wc = wave & 1;
    const int fr = lane & 15;
    const int slr = lane >> 4;
    int offA[4], offB[4];
#pragma unroll
    for (int i = 0; i < 4; ++i) {
        offA[i] = lds_off(wr * 64 + i * 16 + fr, slr);
        offB[i] = lds_off(wc * 64 + i * 16 + fr, slr);
    }

    f32x4 acc[4][4] = {};
    const int NT = K / BK;

    float4 va[4], vb[4];
#pragma unroll
    for (int p = 0; p < 4; ++p) {
        va[p] = *reinterpret_cast<const float4*>(gA + p * 4);
        vb[p] = *reinterpret_cast<const float4*>(gB + p * 4);
    }

    for (int t = 0; t < NT; ++t) {
        const int cur = t & 1;
        u16x8 pa0, pa1, pb0, pb1;
#pragma unroll
        for (int e = 0; e < 4; ++e) {
            pa0[e] = f2bf(va[0][e]);  pa0[4 + e] = f2bf(va[1][e]);
            pa1[e] = f2bf(va[2][e]);  pa1[4 + e] = f2bf(va[3][e]);
            pb0[e] = f2bf(vb[0][e]);  pb0[4 + e] = f2bf(vb[1][e]);
            pb1[e] = f2bf(vb[2][e]);  pb1[4 + e] = f2bf(vb[3][e]);
        }
        *reinterpret_cast<u16x8*>(&sA[cur][wo0]) = pa0;
        *reinterpret_cast<u16x8*>(&sA[cur][wo1]) = pa1;
        *reinterpret_cast<u16x8*>(&sB[cur][wo0]) = pb0;
        *reinterpret_cast<u16x8*>(&sB[cur][wo1]) = pb1;

        const int kn = (t + 1 < NT) ? (t + 1) * BK : t * BK;
#pragma unroll
        for (int p = 0; p < 4; ++p) {
            va[p] = *reinterpret_cast<const float4*>(gA + kn + p * 4);
            vb[p] = *reinterpret_cast<const float4*>(gB + kn + p * 4);
        }

        __syncthreads();

        bf16x8 a[4], b[4];
#pragma unroll
        for (int i = 0; i < 4; ++i) a[i] = *reinterpret_cast<const bf16x8*>(&sA[cur][offA[i]]);
#pragma unroll
        for (int j = 0; j < 4; ++j) b[j] = *reinterpret_cast<const bf16x8*>(&sB[cur][offB[j]]);
#pragma unroll
        for (int i = 0; i < 4; ++i)
#pragma unroll
            for (int j = 0; j < 4; ++j)
                acc[i][j] = __builtin_amdgcn_mfma_f32_16x16x32_bf16(a[i], b[j], acc[i][j], 0, 0, 0);
    }

    const int crow0 = bm * BM + wr * 64 + (lane >> 4) * 4;
    const int ccol0 = bn * BN + wc * 64 + fr;
#pragma unroll
    for (int i = 0; i < 4; ++i)
#pragma unroll
        for (int j = 0; j < 4; ++j)
#pragma unroll
            for (int r = 0; r < 4; ++r)
                C[(size_t)(crow0 + i * 16 + r) * N + (ccol0 + j * 16)] = acc[i][j][r];
}

extern "C" void kernel_launch(void* const* d_in, const int* in_sizes, int n_in,
                              void* d_out, int out_size, void* d_ws, size_t ws_size,
                              hipStream_t stream) {
    int K = 4096;
    int M = in_sizes[0] / K;   // 2048
    int N = in_sizes[1] / K;   // 8192

    const float* x = (const float*)d_in[0];
    const float* w = (const float*)d_in[1];
    float* out     = (float*)d_out;
    unsigned short* wsp = (unsigned short*)d_ws;

    const size_t szX = (size_t)in_sizes[0], szW = (size_t)in_sizes[1];
    const size_t cntOff = (((szX + szW) * 2) + 255) & ~(size_t)255;
    const size_t need = cntOff + 256;
    unsigned int* cnt = (unsigned int*)((char*)d_ws + cntOff);

    const int nwg2 = (M >> 8) * (N >> 8);   // 256 = 1 block/CU on MI355X

    // Pure-arithmetic path selection: NO runtime API calls (identical result
    // inside and outside graph capture). Co-residency is static: 256 blocks
    // on 256 CUs, 128 KB LDS <= 160 KB, 512 thr, 112 VGPR -> 1 block/CU fits.
    const bool pers_ok = (M % 256 == 0) && (N % 256 == 0) && (K % 64 == 0) &&
                         ((nwg2 & 7) == 0) && (nwg2 <= 256) && (ws_size >= need);

    if (pers_ok) {
        reset_cnt<<<dim3(1), dim3(1), 0, stream>>>(cnt);
        persist_cvt_gemm<<<dim3(nwg2), dim3(512), 0, stream>>>(x, w, wsp, cnt, out, M, N, K);
        return;
    }
    const int nwg = (M / 128) * (N / 128);
    gemm_bt_fused<<<dim3(nwg), dim3(256), 0, stream>>>(x, w, out, M, N, K);
}